// Round 3
// baseline (1226.425 us; speedup 1.0000x reference)
//
#include <hip/hip_runtime.h>
#include <cstdint>
#include <cstddef>

#define NE 8
#define DMODEL 768
#define MLPDIM 3072
#define NDET 16384
#define NCLS 4096
#define NTOK 20480
#define ROWS_PER_E 5120   /* 16*256 (det) + 8*128 (cls) */
#define TOT_ROWS 40960

typedef float f32x4 __attribute__((ext_vector_type(4)));
typedef __bf16 bf16x8 __attribute__((ext_vector_type(8)));

__device__ __forceinline__ unsigned short f2bf(float f) {
    unsigned u = __float_as_uint(f);
    u += 0x7FFFu + ((u >> 16) & 1u);   // RNE
    return (unsigned short)(u >> 16);
}
__device__ __forceinline__ float bf2f(unsigned v) {
    return __uint_as_float(v << 16);
}
__device__ __forceinline__ float gelu_f(float x) {
    // jax.nn.gelu approximate=True (tanh form)
    float u = 0.7978845608028654f * (x + 0.044715f * x * x * x);
    float a = fabsf(u);
    float t = __expf(-2.0f * a);
    float th = (1.0f - t) / (1.0f + t);
    th = (u >= 0.0f) ? th : -th;
    return 0.5f * x * (1.0f + th);
}

// async global->LDS, 16B per lane; dst is wave-uniform base, HW adds lane*16
__device__ __forceinline__ void gload16(const void* g, void* l) {
    __builtin_amdgcn_global_load_lds(
        (const __attribute__((address_space(1))) unsigned int*)g,
        (__attribute__((address_space(3))) unsigned int*)l, 16, 0, 0);
}

// ---------------- router (fp32) + x->bf16 conversion fused ----------------
__global__ void k_router(const float* __restrict__ xd, const float* __restrict__ xc,
                         const float* __restrict__ wrd, const float* __restrict__ wrc,
                         ushort* __restrict__ xbf,
                         int* __restrict__ e1, int* __restrict__ e2,
                         float* __restrict__ g1, float* __restrict__ g2) {
    int wave = threadIdx.x >> 6, lane = threadIdx.x & 63;
    int t = blockIdx.x * 4 + wave;
    if (t >= NTOK) return;
    const float* xrow;
    const float* w;
    if (t < NDET) { xrow = xd + (size_t)t * DMODEL; w = wrd; }
    else          { xrow = xc + (size_t)(t - NDET) * DMODEL; w = wrc; }
    ushort* xbrow = xbf + (size_t)t * DMODEL;
    float acc[8];
    #pragma unroll
    for (int e = 0; e < 8; e++) acc[e] = 0.0f;
    #pragma unroll
    for (int kk = 0; kk < DMODEL / 64; kk++) {
        int k = kk * 64 + lane;
        float xv = xrow[k];
        xbrow[k] = f2bf(xv);              // fused bf16 conversion
        const float* wr = w + k * 8;
        #pragma unroll
        for (int e = 0; e < 8; e++) acc[e] += xv * wr[e];
    }
    #pragma unroll
    for (int e = 0; e < 8; e++) {
        #pragma unroll
        for (int off = 32; off > 0; off >>= 1) acc[e] += __shfl_xor(acc[e], off);
    }
    // top-2 with lower-index tie-break (lax.top_k)
    int i1 = 0; float v1 = acc[0];
    #pragma unroll
    for (int e = 1; e < 8; e++) if (acc[e] > v1) { v1 = acc[e]; i1 = e; }
    int i2 = -1; float v2 = -1e30f;
    #pragma unroll
    for (int e = 0; e < 8; e++) if (e != i1 && acc[e] > v2) { v2 = acc[e]; i2 = e; }
    float Z = 0.0f;
    #pragma unroll
    for (int e = 0; e < 8; e++) Z += __expf(acc[e] - v1);
    if (lane == 0) {
        e1[t] = i1; e2[t] = i2;
        g1[t] = 1.0f / Z;
        g2[t] = __expf(v2 - v1) / Z;
    }
}

// ---------------- w [E][K][N] fp32 -> [E][N][K] bf16 ----------------
__global__ void k_transpose_bf(const float* __restrict__ in, ushort* __restrict__ out,
                               int K, int N) {
    __shared__ float tile[32][33];
    int e = blockIdx.z;
    const float* A = in + (size_t)e * K * N;
    ushort* B = out + (size_t)e * N * K;
    int n0 = blockIdx.x * 32, k0 = blockIdx.y * 32;
    for (int i = threadIdx.y; i < 32; i += 8)
        tile[i][threadIdx.x] = A[(size_t)(k0 + i) * N + n0 + threadIdx.x];
    __syncthreads();
    for (int i = threadIdx.y; i < 32; i += 8)
        B[(size_t)(n0 + i) * K + k0 + threadIdx.x] = f2bf(tile[threadIdx.x][i]);
}

// ---------------- capacity scan: one wave per group, k-major order ----------------
__global__ void k_scan(const int* __restrict__ e1, const int* __restrict__ e2,
                       int* __restrict__ slot_map, int* __restrict__ r1, int* __restrict__ r2) {
    int g = blockIdx.x;          // 0..15 det, 16..23 cls
    int lane = threadIdx.x;      // 64 threads
    int S, C, base;
    if (g < 16) { S = 1024; C = 256; base = g * 1024; }
    else        { S = 512;  C = 128; base = NDET + (g - 16) * 512; }
    int cnt[8];
    #pragma unroll
    for (int e = 0; e < 8; e++) cnt[e] = 0;
    unsigned long long lower = (lane == 0) ? 0ULL : ((~0ULL) >> (64 - lane));
    int nch = (2 * S) >> 6;
    for (int ch = 0; ch < nch; ch++) {
        int n = ch * 64 + lane;
        int k = (n >= S) ? 1 : 0;
        int s = n - k * S;
        int tok = base + s;
        int e = k ? e2[tok] : e1[tok];
        int pos = 0;
        #pragma unroll
        for (int ee = 0; ee < 8; ee++) {
            unsigned long long m = __ballot(e == ee);
            if (e == ee) pos = cnt[ee] + __popcll(m & lower);
            cnt[ee] += __popcll(m);
        }
        int r = -1;
        if (pos < C) {
            int local = (g < 16) ? (g * 256 + pos) : (4096 + (g - 16) * 128 + pos);
            r = e * ROWS_PER_E + local;
            slot_map[r] = tok;
        }
        if (k == 0) r1[tok] = r; else r2[tok] = r;
    }
}

// ---------------- GEMM block: 128x128 tile, BK=64, XOR-swizzled LDS ----------------
// LDS layout: [128 rows][64 cols] bf16, 128B rows. Physical 16B chunk p of row r
// holds global chunk p ^ (r&7)  (rule #21: linear LDS dest for global_load_lds,
// inverse-swizzled per-lane GLOBAL source, same XOR on the ds_read side).
template<int KTOT, int NTOT, bool GELU>
__device__ __forceinline__ void gemm_block(
    int mb, int nb,
    const ushort* __restrict__ Asrc, const int* __restrict__ smap,
    const ushort* __restrict__ Bt, const float* __restrict__ bias,
    ushort* __restrict__ Cout, ushort* As, ushort* Bs) {
    constexpr int KSTEPS = KTOT / 64;
    const int m0 = mb * 128, n0 = nb * 128;
    const int t = threadIdx.x, lane = t & 63, wave = t >> 6;
    const int g8 = lane >> 3;          // row-in-group 0..7 (== r&7, groups 8-aligned)
    const int p8 = lane & 7;           // physical chunk this lane fills
    const int swz = ((p8 ^ g8) << 4);  // byte offset of the LOGICAL chunk to fetch

    // staging sources: wave covers rows [wave*32, wave*32+32) of As and Bs,
    // 4 gloads each (8 rows x 128B per gload)
    const char* aS[4];
    const char* bS[4];
    #pragma unroll
    for (int j = 0; j < 4; j++) {
        int ar = m0 + wave * 32 + j * 8 + g8;
        int tok = ar;
        if (smap) { int tk = smap[ar]; tok = (tk < 0) ? 0 : tk; }
        aS[j] = (const char*)(Asrc + (size_t)tok * KTOT) + swz;
        bS[j] = (const char*)(Bt + (size_t)(n0 + wave * 32 + j * 8 + g8) * KTOT) + swz;
    }

    auto ISSUE = [&](int ks) {
        int o = ks * 128;
        #pragma unroll
        for (int j = 0; j < 4; j++) {
            gload16(aS[j] + o, As + (wave * 32 + j * 8) * 64);
            gload16(bS[j] + o, Bs + (wave * 32 + j * 8) * 64);
        }
    };

    const int wr = wave >> 1, wc = wave & 1;
    const int arow = wr * 64 + (lane & 15);
    const int brow = wc * 64 + (lane & 15);
    const int kq = lane >> 4, l7 = lane & 7;
    const int ch0 = ((kq) ^ l7) << 3;        // ushort offset, kk=0 chunk
    const int ch1 = ((4 + kq) ^ l7) << 3;    // kk=1 chunk

    f32x4 acc[4][4] = {};
    ISSUE(0);
    for (int ks = 0; ks < KSTEPS; ks++) {
        __syncthreads();               // drains vmcnt: tile ks visible in LDS
        bf16x8 a0[4], b0[4], a1[4], b1[4];
        #pragma unroll
        for (int mt = 0; mt < 4; mt++)
            a0[mt] = *(const bf16x8*)(As + (arow + mt * 16) * 64 + ch0);
        #pragma unroll
        for (int nt = 0; nt < 4; nt++)
            b0[nt] = *(const bf16x8*)(Bs + (brow + nt * 16) * 64 + ch0);
        #pragma unroll
        for (int mt = 0; mt < 4; mt++)
            a1[mt] = *(const bf16x8*)(As + (arow + mt * 16) * 64 + ch1);
        #pragma unroll
        for (int nt = 0; nt < 4; nt++)
            b1[nt] = *(const bf16x8*)(Bs + (brow + nt * 16) * 64 + ch1);
        __syncthreads();               // all waves done reading LDS
        if (ks + 1 < KSTEPS) ISSUE(ks + 1);   // async loads overlap MFMA
        #pragma unroll
        for (int mt = 0; mt < 4; mt++) {
            #pragma unroll
            for (int nt = 0; nt < 4; nt++)
                acc[mt][nt] = __builtin_amdgcn_mfma_f32_16x16x32_bf16(a0[mt], b0[nt], acc[mt][nt], 0, 0, 0);
        }
        #pragma unroll
        for (int mt = 0; mt < 4; mt++) {
            #pragma unroll
            for (int nt = 0; nt < 4; nt++)
                acc[mt][nt] = __builtin_amdgcn_mfma_f32_16x16x32_bf16(a1[mt], b1[nt], acc[mt][nt], 0, 0, 0);
        }
    }

    // epilogue: C/D layout col=lane&15, row=(lane>>4)*4+j  (verified)
    const int crow_base = m0 + wr * 64;
    const int ccol_base = n0 + wc * 64;
    #pragma unroll
    for (int nt = 0; nt < 4; nt++) {
        int col = ccol_base + nt * 16 + (lane & 15);
        float bv = bias[col];
        #pragma unroll
        for (int mt = 0; mt < 4; mt++) {
            #pragma unroll
            for (int j = 0; j < 4; j++) {
                int row = crow_base + mt * 16 + (lane >> 4) * 4 + j;
                float v = acc[mt][nt][j] + bv;
                if (GELU) v = gelu_f(v);
                Cout[(size_t)row * NTOT + col] = f2bf(v);
            }
        }
    }
}

// unified dispatch: first nb1 (swizzled) blocks run GEMM1(expert e), rest GEMM2(expert e-1)
__global__ __launch_bounds__(256) void k_mlp(
    int nb1,
    const ushort* __restrict__ xbf, const int* __restrict__ smap,
    const ushort* __restrict__ w1t, const float* __restrict__ b1, ushort* __restrict__ h,
    const ushort* __restrict__ hin, const ushort* __restrict__ w2t, const float* __restrict__ b2,
    ushort* __restrict__ y) {
    __shared__ __align__(1024) ushort As[128 * 64];
    __shared__ __align__(1024) ushort Bs[128 * 64];
    // bijective XCD-chunked swizzle (gridDim.x % 8 == 0)
    const int q = gridDim.x >> 3;
    const int id2 = (blockIdx.x & 7) * q + (blockIdx.x >> 3);
    if (id2 < nb1) {
        int mb = id2 / (MLPDIM / 128), nb = id2 - mb * (MLPDIM / 128);
        gemm_block<DMODEL, MLPDIM, true>(mb, nb, xbf, smap, w1t, b1, h, As, Bs);
    } else {
        int id3 = id2 - nb1;
        int mb = id3 / (DMODEL / 128), nb = id3 - mb * (DMODEL / 128);
        gemm_block<MLPDIM, DMODEL, false>(mb, nb, hin, nullptr, w2t, b2, y, As, Bs);
    }
}

// ---------------- combine: out[token] = g1*y[r1] + g2*y[r2] ----------------
__global__ void k_combine(const ushort* __restrict__ y,
                          const int* __restrict__ r1, const int* __restrict__ r2,
                          const float* __restrict__ g1, const float* __restrict__ g2,
                          float* __restrict__ out) {
    int t = blockIdx.x;
    int d = threadIdx.x;          // 192 threads, 4 floats each
    int a = r1[t], b = r2[t];
    float wa = g1[t], wb = g2[t];
    size_t opos;
    if (t < NDET) { int bb = t >> 10, s = t & 1023; opos = ((size_t)bb * 1280 + s) * 768; }
    else { int tt = t - NDET; int bb = tt >> 8, s = tt & 255; opos = ((size_t)bb * 1280 + 1024 + s) * 768; }
    int di = d * 4;
    float4 o = make_float4(0.f, 0.f, 0.f, 0.f);
    if (a >= 0) {
        uint2 v = *(const uint2*)(y + (size_t)a * 768 + di);
        o.x += wa * bf2f(v.x & 0xffffu); o.y += wa * bf2f(v.x >> 16);
        o.z += wa * bf2f(v.y & 0xffffu); o.w += wa * bf2f(v.y >> 16);
    }
    if (b >= 0) {
        uint2 v = *(const uint2*)(y + (size_t)b * 768 + di);
        o.x += wb * bf2f(v.x & 0xffffu); o.y += wb * bf2f(v.x >> 16);
        o.z += wb * bf2f(v.y & 0xffffu); o.w += wb * bf2f(v.y >> 16);
    }
    *(float4*)(out + opos + di) = o;
}

extern "C" void kernel_launch(void* const* d_in, const int* in_sizes, int n_in,
                              void* d_out, int out_size, void* d_ws, size_t ws_size,
                              hipStream_t stream) {
    const float* xd  = (const float*)d_in[0];
    const float* xc  = (const float*)d_in[1];
    const float* wrd = (const float*)d_in[2];
    const float* wrc = (const float*)d_in[3];
    const float* w1  = (const float*)d_in[4];
    const float* b1  = (const float*)d_in[5];
    const float* w2  = (const float*)d_in[6];
    const float* b2  = (const float*)d_in[7];
    float* out = (float*)d_out;

    size_t off = 0;
    char* base = (char*)d_ws;
    auto alloc = [&](size_t bytes) -> char* {
        char* r = base + off;
        off += (bytes + 255) & ~(size_t)255;
        return r;
    };
    ushort* xbf = (ushort*)alloc((size_t)NTOK * DMODEL * 2);
    ushort* w1t = (ushort*)alloc((size_t)NE * MLPDIM * DMODEL * 2);
    ushort* w2t = (ushort*)alloc((size_t)NE * DMODEL * MLPDIM * 2);
    ushort* y   = (ushort*)alloc((size_t)TOT_ROWS * DMODEL * 2);
    int*   slot_map = (int*)alloc((size_t)TOT_ROWS * 4);
    int*   e1 = (int*)alloc((size_t)NTOK * 4);
    int*   e2 = (int*)alloc((size_t)NTOK * 4);
    float* g1 = (float*)alloc((size_t)NTOK * 4);
    float* g2 = (float*)alloc((size_t)NTOK * 4);
    int*   r1 = (int*)alloc((size_t)NTOK * 4);
    int*   r2 = (int*)alloc((size_t)NTOK * 4);

    const size_t h_bytes = (size_t)ROWS_PER_E * MLPDIM * 2;   // 31.5 MB
    ushort* h0 = (ushort*)alloc(h_bytes);
    bool pipelined = (ws_size >= off + h_bytes);               // room for 2nd h buffer?
    ushort* h1 = pipelined ? (ushort*)alloc(h_bytes) : h0;
    if (off > ws_size) return;   // ws too small even for fallback

    hipMemsetAsync(slot_map, 0xFF, (size_t)TOT_ROWS * 4, stream);   // -1 = empty slot

    k_router<<<NTOK / 4, 256, 0, stream>>>(xd, xc, wrd, wrc, xbf, e1, e2, g1, g2);
    k_transpose_bf<<<dim3(MLPDIM / 32, DMODEL / 32, NE), dim3(32, 8), 0, stream>>>(w1, w1t, DMODEL, MLPDIM);
    k_transpose_bf<<<dim3(DMODEL / 32, MLPDIM / 32, NE), dim3(32, 8), 0, stream>>>(w2, w2t, MLPDIM, DMODEL);
    k_scan<<<24, 64, 0, stream>>>(e1, e2, slot_map, r1, r2);

    const int NB1 = (ROWS_PER_E / 128) * (MLPDIM / 128);   // 960
    const int NB2 = (ROWS_PER_E / 128) * (DMODEL / 128);   // 240
    ushort* hbuf[2] = { h0, h1 };

    if (pipelined) {
        // dispatch d: GEMM1(expert d) [d<8]  ||  GEMM2(expert d-1) [d>=1]
        for (int d = 0; d <= NE; d++) {
            int nb1 = (d < NE) ? NB1 : 0;
            int nb2 = (d > 0) ? NB2 : 0;
            int e1i = (d < NE) ? d : 0;
            int e2i = (d > 0) ? d - 1 : 0;
            k_mlp<<<nb1 + nb2, 256, 0, stream>>>(
                nb1,
                xbf, slot_map + (size_t)e1i * ROWS_PER_E,
                w1t + (size_t)e1i * MLPDIM * DMODEL, b1 + (size_t)e1i * MLPDIM, hbuf[e1i & 1],
                hbuf[e2i & 1], w2t + (size_t)e2i * DMODEL * MLPDIM, b2 + (size_t)e2i * DMODEL,
                y + (size_t)e2i * ROWS_PER_E * DMODEL);
        }
    } else {
        for (int e = 0; e < NE; e++) {
            k_mlp<<<NB1, 256, 0, stream>>>(
                NB1, xbf, slot_map + (size_t)e * ROWS_PER_E,
                w1t + (size_t)e * MLPDIM * DMODEL, b1 + (size_t)e * MLPDIM, h0,
                h0, w2t, b2, y);
            k_mlp<<<NB2, 256, 0, stream>>>(
                0, xbf, slot_map,
                w1t, b1, h0,
                h0, w2t + (size_t)e * DMODEL * MLPDIM, b2 + (size_t)e * DMODEL,
                y + (size_t)e * ROWS_PER_E * DMODEL);
        }
    }

    k_combine<<<NTOK, 192, 0, stream>>>(y, r1, r2, g1, g2, out);
}

// Round 4
// 763.610 us; speedup vs baseline: 1.6061x; 1.6061x over previous
//
#include <hip/hip_runtime.h>
#include <cstdint>
#include <cstddef>

#define NE 8
#define DMODEL 768
#define MLPDIM 3072
#define NDET 16384
#define NCLS 4096
#define NTOK 20480
#define ROWS_PER_E 5120   /* 16*256 (det) + 8*128 (cls) */
#define TOT_ROWS 40960

typedef float f32x4 __attribute__((ext_vector_type(4)));
typedef __bf16 bf16x8 __attribute__((ext_vector_type(8)));

__device__ __forceinline__ unsigned short f2bf(float f) {
    unsigned u = __float_as_uint(f);
    u += 0x7FFFu + ((u >> 16) & 1u);   // RNE
    return (unsigned short)(u >> 16);
}
__device__ __forceinline__ float gelu_f(float x) {
    // jax.nn.gelu approximate=True (tanh form)
    float u = 0.7978845608028654f * (x + 0.044715f * x * x * x);
    float a = fabsf(u);
    float t = __expf(-2.0f * a);
    float th = (1.0f - t) / (1.0f + t);
    th = (u >= 0.0f) ? th : -th;
    return 0.5f * x * (1.0f + th);
}

// async global->LDS, 16B per lane; dst is wave-uniform base, HW adds lane*16
__device__ __forceinline__ void gload16(const void* g, void* l) {
    __builtin_amdgcn_global_load_lds(
        (const __attribute__((address_space(1))) unsigned int*)g,
        (__attribute__((address_space(3))) unsigned int*)l, 16, 0, 0);
}

// ---------------- router (fp32) + x->bf16 conversion fused ----------------
__global__ void k_router(const float* __restrict__ xd, const float* __restrict__ xc,
                         const float* __restrict__ wrd, const float* __restrict__ wrc,
                         ushort* __restrict__ xbf,
                         int* __restrict__ e1, int* __restrict__ e2,
                         float* __restrict__ g1, float* __restrict__ g2) {
    int wave = threadIdx.x >> 6, lane = threadIdx.x & 63;
    int t = blockIdx.x * 4 + wave;
    if (t >= NTOK) return;
    const float* xrow;
    const float* w;
    if (t < NDET) { xrow = xd + (size_t)t * DMODEL; w = wrd; }
    else          { xrow = xc + (size_t)(t - NDET) * DMODEL; w = wrc; }
    ushort* xbrow = xbf + (size_t)t * DMODEL;
    float acc[8];
    #pragma unroll
    for (int e = 0; e < 8; e++) acc[e] = 0.0f;
    #pragma unroll
    for (int kk = 0; kk < DMODEL / 64; kk++) {
        int k = kk * 64 + lane;
        float xv = xrow[k];
        xbrow[k] = f2bf(xv);              // fused bf16 conversion
        const float* wr = w + k * 8;
        #pragma unroll
        for (int e = 0; e < 8; e++) acc[e] += xv * wr[e];
    }
    #pragma unroll
    for (int e = 0; e < 8; e++) {
        #pragma unroll
        for (int off = 32; off > 0; off >>= 1) acc[e] += __shfl_xor(acc[e], off);
    }
    // top-2 with lower-index tie-break (lax.top_k)
    int i1 = 0; float v1 = acc[0];
    #pragma unroll
    for (int e = 1; e < 8; e++) if (acc[e] > v1) { v1 = acc[e]; i1 = e; }
    int i2 = -1; float v2 = -1e30f;
    #pragma unroll
    for (int e = 0; e < 8; e++) if (e != i1 && acc[e] > v2) { v2 = acc[e]; i2 = e; }
    float Z = 0.0f;
    #pragma unroll
    for (int e = 0; e < 8; e++) Z += __expf(acc[e] - v1);
    if (lane == 0) {
        e1[t] = i1; e2[t] = i2;
        g1[t] = 1.0f / Z;
        g2[t] = __expf(v2 - v1) / Z;
    }
}

// ---------------- w [E][K][N] fp32 -> [E][N][K] bf16 (float4 loads) ----------------
__global__ void k_transpose_bf(const float* __restrict__ in, ushort* __restrict__ out,
                               int K, int N) {
    __shared__ float tile[32][33];
    int e = blockIdx.z;
    const float* A = in + (size_t)e * K * N;
    ushort* B = out + (size_t)e * N * K;
    int n0 = blockIdx.x * 32, k0 = blockIdx.y * 32;
    int tx = threadIdx.x, ty = threadIdx.y;   // (8,32)
    float4 v = *(const float4*)(A + (size_t)(k0 + ty) * N + n0 + tx * 4);
    tile[ty][tx * 4 + 0] = v.x; tile[ty][tx * 4 + 1] = v.y;
    tile[ty][tx * 4 + 2] = v.z; tile[ty][tx * 4 + 3] = v.w;
    __syncthreads();
    ushort4 o;
    o.x = f2bf(tile[tx * 4 + 0][ty]);
    o.y = f2bf(tile[tx * 4 + 1][ty]);
    o.z = f2bf(tile[tx * 4 + 2][ty]);
    o.w = f2bf(tile[tx * 4 + 3][ty]);
    *(ushort4*)(B + (size_t)(n0 + ty) * K + k0 + tx * 4) = o;
}

// ---------------- capacity scan: one wave per group, k-major order ----------------
// writes slot_map[row]=tok and gsl[row]=gate for kept slots
__global__ void k_scan(const int* __restrict__ e1, const int* __restrict__ e2,
                       const float* __restrict__ g1, const float* __restrict__ g2,
                       int* __restrict__ slot_map, float* __restrict__ gsl) {
    int g = blockIdx.x;          // 0..15 det, 16..23 cls
    int lane = threadIdx.x;      // 64 threads
    int S, C, base;
    if (g < 16) { S = 1024; C = 256; base = g * 1024; }
    else        { S = 512;  C = 128; base = NDET + (g - 16) * 512; }
    int cnt[8];
    #pragma unroll
    for (int e = 0; e < 8; e++) cnt[e] = 0;
    unsigned long long lower = (lane == 0) ? 0ULL : ((~0ULL) >> (64 - lane));
    int nch = (2 * S) >> 6;
    for (int ch = 0; ch < nch; ch++) {
        int n = ch * 64 + lane;
        int k = (n >= S) ? 1 : 0;
        int s = n - k * S;
        int tok = base + s;
        int e = k ? e2[tok] : e1[tok];
        int pos = 0;
        #pragma unroll
        for (int ee = 0; ee < 8; ee++) {
            unsigned long long m = __ballot(e == ee);
            if (e == ee) pos = cnt[ee] + __popcll(m & lower);
            cnt[ee] += __popcll(m);
        }
        if (pos < C) {
            int local = (g < 16) ? (g * 256 + pos) : (4096 + (g - 16) * 128 + pos);
            int r = e * ROWS_PER_E + local;
            slot_map[r] = tok;
            gsl[r] = k ? g2[tok] : g1[tok];
        }
    }
}

// ---------------- GEMM: 128x128 tile, BK=64, XOR-swizzled LDS ----------------
// MODE 0: A = xbf gathered via slot_map, C = gelu(A@B+b) -> h  (chunk-local rows)
// MODE 1: A = h (chunk-local),  scatter-add gate*(A@B+b) into out via slot_map
// mb spans chunkE*40 m-blocks; expert = eBase + mb/40.
template<int KTOT, int NTOT, int MODE>
__global__ __launch_bounds__(256) void k_gemm(
    const ushort* __restrict__ Asrc, const int* __restrict__ slot_map,
    const ushort* __restrict__ wtBase, const float* __restrict__ biasBase,
    ushort* __restrict__ hout, float* __restrict__ out, const float* __restrict__ gsl,
    int eBase) {
    constexpr int KSTEPS = KTOT / 64;
    constexpr int NBN = NTOT / 128;
    __shared__ __align__(1024) ushort As[128 * 64];
    __shared__ __align__(1024) ushort Bs[128 * 64];

    // bijective XCD-chunked swizzle (gridDim.x % 8 == 0)
    const int q = gridDim.x >> 3;
    const int id2 = (blockIdx.x & 7) * q + (blockIdx.x >> 3);
    const int mb = id2 / NBN, nb = id2 - mb * NBN;
    const int e = eBase + mb / (ROWS_PER_E / 128);
    const int m0 = mb * 128;          // chunk-local row base
    const int rbase = eBase * ROWS_PER_E + m0;   // global row base (slot_map/gsl)
    const int n0 = nb * 128;
    const ushort* Bt = wtBase + (size_t)e * KTOT * NTOT;
    const float* bias = biasBase + (size_t)e * NTOT;

    const int t = threadIdx.x, lane = t & 63, wave = t >> 6;
    const int g8 = lane >> 3;          // row within 8-row group
    const int p8 = lane & 7;           // physical 16B chunk this lane fills
    const int swz = ((p8 ^ g8) << 4);  // byte offset of LOGICAL chunk to fetch

    const char* aS[4];
    const char* bS[4];
    #pragma unroll
    for (int j = 0; j < 4; j++) {
        int r = wave * 32 + j * 8 + g8;
        size_t arow;
        if (MODE == 0) { int tk = slot_map[rbase + r]; arow = (size_t)(tk < 0 ? 0 : tk); }
        else           { arow = (size_t)(m0 + r); }
        aS[j] = (const char*)(Asrc + arow * KTOT) + swz;
        bS[j] = (const char*)(Bt + (size_t)(n0 + r) * KTOT) + swz;
    }

    auto ISSUE = [&](int ks) {
        int o = ks * 128;
        #pragma unroll
        for (int j = 0; j < 4; j++) {
            gload16(aS[j] + o, As + (wave * 32 + j * 8) * 64);
            gload16(bS[j] + o, Bs + (wave * 32 + j * 8) * 64);
        }
    };

    const int wr = wave >> 1, wc = wave & 1;
    const int arow = wr * 64 + (lane & 15);
    const int brow = wc * 64 + (lane & 15);
    const int kq = lane >> 4, l7 = lane & 7;
    const int ch0 = ((kq) ^ l7) << 3;        // ushort offset, first 32 k
    const int ch1 = ((4 + kq) ^ l7) << 3;    // second 32 k

    f32x4 acc[4][4] = {};
    ISSUE(0);
    for (int ks = 0; ks < KSTEPS; ks++) {
        __syncthreads();               // drains vmcnt: tile ks visible in LDS
        bf16x8 a0[4], b0[4], a1[4], b1[4];
        #pragma unroll
        for (int mt = 0; mt < 4; mt++)
            a0[mt] = *(const bf16x8*)(As + (arow + mt * 16) * 64 + ch0);
        #pragma unroll
        for (int nt = 0; nt < 4; nt++)
            b0[nt] = *(const bf16x8*)(Bs + (brow + nt * 16) * 64 + ch0);
        #pragma unroll
        for (int mt = 0; mt < 4; mt++)
            a1[mt] = *(const bf16x8*)(As + (arow + mt * 16) * 64 + ch1);
        #pragma unroll
        for (int nt = 0; nt < 4; nt++)
            b1[nt] = *(const bf16x8*)(Bs + (brow + nt * 16) * 64 + ch1);
        __syncthreads();               // all waves done reading LDS
        if (ks + 1 < KSTEPS) ISSUE(ks + 1);   // async loads overlap MFMA
        #pragma unroll
        for (int mt = 0; mt < 4; mt++) {
            #pragma unroll
            for (int nt = 0; nt < 4; nt++)
                acc[mt][nt] = __builtin_amdgcn_mfma_f32_16x16x32_bf16(a0[mt], b0[nt], acc[mt][nt], 0, 0, 0);
        }
        #pragma unroll
        for (int mt = 0; mt < 4; mt++) {
            #pragma unroll
            for (int nt = 0; nt < 4; nt++)
                acc[mt][nt] = __builtin_amdgcn_mfma_f32_16x16x32_bf16(a1[mt], b1[nt], acc[mt][nt], 0, 0, 0);
        }
    }

    // epilogue: C/D layout col=lane&15, row=(lane>>4)*4+j  (verified)
    const int ccol = wc * 64 + (lane & 15);
    float bv[4];
    #pragma unroll
    for (int nt = 0; nt < 4; nt++) bv[nt] = bias[n0 + ccol + nt * 16];

    if (MODE == 0) {
        #pragma unroll
        for (int mt = 0; mt < 4; mt++) {
            #pragma unroll
            for (int j = 0; j < 4; j++) {
                int row = m0 + wr * 64 + mt * 16 + (lane >> 4) * 4 + j;
                #pragma unroll
                for (int nt = 0; nt < 4; nt++) {
                    float v = gelu_f(acc[mt][nt][j] + bv[nt]);
                    hout[(size_t)row * NTOT + n0 + ccol + nt * 16] = f2bf(v);
                }
            }
        }
    } else {
        #pragma unroll
        for (int mt = 0; mt < 4; mt++) {
            #pragma unroll
            for (int j = 0; j < 4; j++) {
                int grow = rbase + wr * 64 + mt * 16 + (lane >> 4) * 4 + j;
                int tok = slot_map[grow];
                if (tok < 0) continue;
                float gate = gsl[grow];
                size_t opos;
                if (tok < NDET) { int bb = tok >> 10, s = tok & 1023; opos = ((size_t)bb * 1280 + s) * 768; }
                else { int tt = tok - NDET; int bb = tt >> 8, s = tt & 255; opos = ((size_t)bb * 1280 + 1024 + s) * 768; }
                #pragma unroll
                for (int nt = 0; nt < 4; nt++) {
                    float v = (acc[mt][nt][j] + bv[nt]) * gate;
                    __hip_atomic_fetch_add(out + opos + n0 + ccol + nt * 16, v,
                                           __ATOMIC_RELAXED, __HIP_MEMORY_SCOPE_AGENT);
                }
            }
        }
    }
}

extern "C" void kernel_launch(void* const* d_in, const int* in_sizes, int n_in,
                              void* d_out, int out_size, void* d_ws, size_t ws_size,
                              hipStream_t stream) {
    const float* xd  = (const float*)d_in[0];
    const float* xc  = (const float*)d_in[1];
    const float* wrd = (const float*)d_in[2];
    const float* wrc = (const float*)d_in[3];
    const float* w1  = (const float*)d_in[4];
    const float* b1  = (const float*)d_in[5];
    const float* w2  = (const float*)d_in[6];
    const float* b2  = (const float*)d_in[7];
    float* out = (float*)d_out;

    size_t off = 0;
    char* base = (char*)d_ws;
    auto alloc = [&](size_t bytes) -> char* {
        char* r = base + off;
        off += (bytes + 255) & ~(size_t)255;
        return r;
    };
    ushort* xbf = (ushort*)alloc((size_t)NTOK * DMODEL * 2);
    ushort* w1t = (ushort*)alloc((size_t)NE * MLPDIM * DMODEL * 2);
    ushort* w2t = (ushort*)alloc((size_t)NE * DMODEL * MLPDIM * 2);
    int*   slot_map = (int*)alloc((size_t)TOT_ROWS * 4);
    float* gsl = (float*)alloc((size_t)TOT_ROWS * 4);
    int*   e1 = (int*)alloc((size_t)NTOK * 4);
    int*   e2 = (int*)alloc((size_t)NTOK * 4);
    float* g1 = (float*)alloc((size_t)NTOK * 4);
    float* g2 = (float*)alloc((size_t)NTOK * 4);

    // pick the largest expert-chunk whose h buffer fits the workspace
    const size_t h_per_e = (size_t)ROWS_PER_E * MLPDIM * 2;   // 31.5 MB
    int chunkE = 0;
    for (int c = NE; c >= 2; c >>= 1)
        if (off + c * h_per_e <= ws_size) { chunkE = c; break; }
    if (!chunkE) return;
    ushort* h = (ushort*)alloc((size_t)chunkE * h_per_e);

    hipMemsetAsync(out, 0, (size_t)out_size * 4, stream);
    hipMemsetAsync(slot_map, 0xFF, (size_t)TOT_ROWS * 4, stream);   // -1 = empty

    k_router<<<NTOK / 4, 256, 0, stream>>>(xd, xc, wrd, wrc, xbf, e1, e2, g1, g2);
    k_transpose_bf<<<dim3(MLPDIM / 32, DMODEL / 32, NE), dim3(8, 32), 0, stream>>>(w1, w1t, DMODEL, MLPDIM);
    k_transpose_bf<<<dim3(DMODEL / 32, MLPDIM / 32, NE), dim3(8, 32), 0, stream>>>(w2, w2t, MLPDIM, DMODEL);
    k_scan<<<24, 64, 0, stream>>>(e1, e2, g1, g2, slot_map, gsl);

    for (int e0 = 0; e0 < NE; e0 += chunkE) {
        int nmb = chunkE * (ROWS_PER_E / 128);               // m-blocks in chunk
        k_gemm<DMODEL, MLPDIM, 0><<<nmb * (MLPDIM / 128), 256, 0, stream>>>(
            xbf, slot_map, w1t, b1, h, nullptr, nullptr, e0);
        k_gemm<MLPDIM, DMODEL, 1><<<nmb * (DMODEL / 128), 256, 0, stream>>>(
            h, slot_map, w2t, b2, nullptr, out, gsl, e0);
    }
}

// Round 5
// 645.298 us; speedup vs baseline: 1.9006x; 1.1833x over previous
//
#include <hip/hip_runtime.h>
#include <cstdint>
#include <cstddef>

#define NE 8
#define DMODEL 768
#define MLPDIM 3072
#define NDET 16384
#define NCLS 4096
#define NTOK 20480
#define ROWS_PER_E 5120   /* 16*256 (det) + 8*128 (cls) */
#define TOT_ROWS 40960

typedef float f32x4 __attribute__((ext_vector_type(4)));
typedef __bf16 bf16x8 __attribute__((ext_vector_type(8)));

__device__ __forceinline__ unsigned short f2bf(float f) {
    unsigned u = __float_as_uint(f);
    u += 0x7FFFu + ((u >> 16) & 1u);   // RNE
    return (unsigned short)(u >> 16);
}
__device__ __forceinline__ float bf2f(unsigned v) {
    return __uint_as_float(v << 16);
}
__device__ __forceinline__ float gelu_f(float x) {
    // jax.nn.gelu approximate=True (tanh form); tanh via exp, sign via copysign
    float u = 0.7978845608028654f * (x + 0.044715f * x * x * x);
    float t = __expf(-2.0f * fabsf(u));
    float th = __builtin_copysignf((1.0f - t) * __frcp_rn(1.0f + t), u);
    return 0.5f * x * (1.0f + th);
}

// async global->LDS, 16B per lane; dst is wave-uniform base, HW adds lane*16
__device__ __forceinline__ void gload16(const void* g, void* l) {
    __builtin_amdgcn_global_load_lds(
        (const __attribute__((address_space(1))) unsigned int*)g,
        (__attribute__((address_space(3))) unsigned int*)l, 16, 0, 0);
}

// ---------------- router (fp32) + x->bf16 conversion fused ----------------
__global__ void k_router(const float* __restrict__ xd, const float* __restrict__ xc,
                         const float* __restrict__ wrd, const float* __restrict__ wrc,
                         ushort* __restrict__ xbf,
                         int* __restrict__ e1, int* __restrict__ e2,
                         float* __restrict__ g1, float* __restrict__ g2) {
    int wave = threadIdx.x >> 6, lane = threadIdx.x & 63;
    int t = blockIdx.x * 4 + wave;
    if (t >= NTOK) return;
    const float* xrow;
    const float* w;
    if (t < NDET) { xrow = xd + (size_t)t * DMODEL; w = wrd; }
    else          { xrow = xc + (size_t)(t - NDET) * DMODEL; w = wrc; }
    ushort* xbrow = xbf + (size_t)t * DMODEL;
    float acc[8];
    #pragma unroll
    for (int e = 0; e < 8; e++) acc[e] = 0.0f;
    #pragma unroll
    for (int kk = 0; kk < DMODEL / 64; kk++) {
        int k = kk * 64 + lane;
        float xv = xrow[k];
        xbrow[k] = f2bf(xv);              // fused bf16 conversion
        const float* wr = w + k * 8;
        #pragma unroll
        for (int e = 0; e < 8; e++) acc[e] += xv * wr[e];
    }
    #pragma unroll
    for (int e = 0; e < 8; e++) {
        #pragma unroll
        for (int off = 32; off > 0; off >>= 1) acc[e] += __shfl_xor(acc[e], off);
    }
    // top-2 with lower-index tie-break (lax.top_k)
    int i1 = 0; float v1 = acc[0];
    #pragma unroll
    for (int e = 1; e < 8; e++) if (acc[e] > v1) { v1 = acc[e]; i1 = e; }
    int i2 = -1; float v2 = -1e30f;
    #pragma unroll
    for (int e = 0; e < 8; e++) if (e != i1 && acc[e] > v2) { v2 = acc[e]; i2 = e; }
    float Z = 0.0f;
    #pragma unroll
    for (int e = 0; e < 8; e++) Z += __expf(acc[e] - v1);
    if (lane == 0) {
        e1[t] = i1; e2[t] = i2;
        g1[t] = 1.0f / Z;
        g2[t] = __expf(v2 - v1) / Z;
    }
}

// ---------------- w [E][K][N] fp32 -> [E][N][K] bf16 (float4 loads) ----------------
__global__ void k_transpose_bf(const float* __restrict__ in, ushort* __restrict__ out,
                               int K, int N) {
    __shared__ float tile[32][33];
    int e = blockIdx.z;
    const float* A = in + (size_t)e * K * N;
    ushort* B = out + (size_t)e * N * K;
    int n0 = blockIdx.x * 32, k0 = blockIdx.y * 32;
    int tx = threadIdx.x, ty = threadIdx.y;   // (8,32)
    float4 v = *(const float4*)(A + (size_t)(k0 + ty) * N + n0 + tx * 4);
    tile[ty][tx * 4 + 0] = v.x; tile[ty][tx * 4 + 1] = v.y;
    tile[ty][tx * 4 + 2] = v.z; tile[ty][tx * 4 + 3] = v.w;
    __syncthreads();
    ushort4 o;
    o.x = f2bf(tile[tx * 4 + 0][ty]);
    o.y = f2bf(tile[tx * 4 + 1][ty]);
    o.z = f2bf(tile[tx * 4 + 2][ty]);
    o.w = f2bf(tile[tx * 4 + 3][ty]);
    *(ushort4*)(B + (size_t)(n0 + ty) * K + k0 + tx * 4) = o;
}

// ---------------- capacity scan: one wave per group, k-major order ----------------
__global__ void k_scan(const int* __restrict__ e1, const int* __restrict__ e2,
                       int* __restrict__ slot_map, int* __restrict__ r1, int* __restrict__ r2) {
    int g = blockIdx.x;          // 0..15 det, 16..23 cls
    int lane = threadIdx.x;      // 64 threads
    int S, C, base;
    if (g < 16) { S = 1024; C = 256; base = g * 1024; }
    else        { S = 512;  C = 128; base = NDET + (g - 16) * 512; }
    int cnt[8];
    #pragma unroll
    for (int e = 0; e < 8; e++) cnt[e] = 0;
    unsigned long long lower = (lane == 0) ? 0ULL : ((~0ULL) >> (64 - lane));
    int nch = (2 * S) >> 6;
    for (int ch = 0; ch < nch; ch++) {
        int n = ch * 64 + lane;
        int k = (n >= S) ? 1 : 0;
        int s = n - k * S;
        int tok = base + s;
        int e = k ? e2[tok] : e1[tok];
        int pos = 0;
        #pragma unroll
        for (int ee = 0; ee < 8; ee++) {
            unsigned long long m = __ballot(e == ee);
            if (e == ee) pos = cnt[ee] + __popcll(m & lower);
            cnt[ee] += __popcll(m);
        }
        int r = -1;
        if (pos < C) {
            int local = (g < 16) ? (g * 256 + pos) : (4096 + (g - 16) * 128 + pos);
            r = e * ROWS_PER_E + local;
            slot_map[r] = tok;
        }
        if (k == 0) r1[tok] = r; else r2[tok] = r;
    }
}

// ---------------- GEMM: 128x128 tile, BK=64, 8 waves, XOR-swizzled LDS ----------------
// 512 threads; wave grid 2(m) x 4(n); per-wave output 64x32 -> acc[4][2] (32 AGPR).
// MODE 0: A = xbf gathered via slot_map, C = gelu(A@B+b) -> h (chunk-local rows)
// MODE 1: A = h (chunk-local), C = A@B+b -> y[global expert row]
template<int KTOT, int NTOT, int MODE>
__global__ __launch_bounds__(512, 4) void k_gemm(
    const ushort* __restrict__ Asrc, const int* __restrict__ slot_map,
    const ushort* __restrict__ wtBase, const float* __restrict__ biasBase,
    ushort* __restrict__ Cdst, int eBase) {
    constexpr int KSTEPS = KTOT / 64;
    constexpr int NBN = NTOT / 128;
    __shared__ __align__(1024) ushort As[128 * 64];
    __shared__ __align__(1024) ushort Bs[128 * 64];

    // bijective XCD-chunked swizzle (gridDim.x % 8 == 0)
    const int q = gridDim.x >> 3;
    const int id2 = (blockIdx.x & 7) * q + (blockIdx.x >> 3);
    const int mb = id2 / NBN, nb = id2 - mb * NBN;
    const int e = eBase + mb / (ROWS_PER_E / 128);
    const int m0 = mb * 128;                     // chunk-local row base
    const int rbase = eBase * ROWS_PER_E + m0;   // global expert-row base
    const int n0 = nb * 128;
    const ushort* Bt = wtBase + (size_t)e * KTOT * NTOT;
    const float* bias = biasBase + (size_t)e * NTOT;

    const int t = threadIdx.x, lane = t & 63, wave = t >> 6;
    const int g8 = lane >> 3;          // row within 8-row group
    const int p8 = lane & 7;           // physical 16B chunk this lane fills
    const int swz = ((p8 ^ g8) << 4);  // byte offset of LOGICAL chunk to fetch

    // each wave stages 16 rows of As and Bs (2 gloads each, 8 rows x 128B per gload)
    const char* aS[2];
    const char* bS[2];
    #pragma unroll
    for (int j = 0; j < 2; j++) {
        int r = wave * 16 + j * 8 + g8;
        size_t arow;
        if (MODE == 0) { int tk = slot_map[rbase + r]; arow = (size_t)(tk < 0 ? 0 : tk); }
        else           { arow = (size_t)(m0 + r); }
        aS[j] = (const char*)(Asrc + arow * KTOT) + swz;
        bS[j] = (const char*)(Bt + (size_t)(n0 + r) * KTOT) + swz;
    }

    auto ISSUE = [&](int ks) {
        int o = ks * 128;
        #pragma unroll
        for (int j = 0; j < 2; j++) {
            gload16(aS[j] + o, As + (wave * 16 + j * 8) * 64);
            gload16(bS[j] + o, Bs + (wave * 16 + j * 8) * 64);
        }
    };

    const int wr = wave >> 2, wc = wave & 3;
    const int arow = wr * 64 + (lane & 15);
    const int brow = wc * 32 + (lane & 15);
    const int kq = lane >> 4, l7 = lane & 7;
    const int ch0 = ((kq) ^ l7) << 3;        // ushort offset, first 32 k
    const int ch1 = ((4 + kq) ^ l7) << 3;    // second 32 k

    f32x4 acc[4][2] = {};
    ISSUE(0);
    for (int ks = 0; ks < KSTEPS; ks++) {
        __syncthreads();               // drains vmcnt: tile ks visible in LDS
        bf16x8 a0[4], b0[2], a1[4], b1[2];
        #pragma unroll
        for (int mt = 0; mt < 4; mt++)
            a0[mt] = *(const bf16x8*)(As + (arow + mt * 16) * 64 + ch0);
        #pragma unroll
        for (int nt = 0; nt < 2; nt++)
            b0[nt] = *(const bf16x8*)(Bs + (brow + nt * 16) * 64 + ch0);
        #pragma unroll
        for (int mt = 0; mt < 4; mt++)
            a1[mt] = *(const bf16x8*)(As + (arow + mt * 16) * 64 + ch1);
        #pragma unroll
        for (int nt = 0; nt < 2; nt++)
            b1[nt] = *(const bf16x8*)(Bs + (brow + nt * 16) * 64 + ch1);
        __syncthreads();               // all waves done reading LDS
        if (ks + 1 < KSTEPS) ISSUE(ks + 1);   // async loads overlap MFMA
        #pragma unroll
        for (int mt = 0; mt < 4; mt++) {
            #pragma unroll
            for (int nt = 0; nt < 2; nt++)
                acc[mt][nt] = __builtin_amdgcn_mfma_f32_16x16x32_bf16(a0[mt], b0[nt], acc[mt][nt], 0, 0, 0);
        }
        #pragma unroll
        for (int mt = 0; mt < 4; mt++) {
            #pragma unroll
            for (int nt = 0; nt < 2; nt++)
                acc[mt][nt] = __builtin_amdgcn_mfma_f32_16x16x32_bf16(a1[mt], b1[nt], acc[mt][nt], 0, 0, 0);
        }
    }

    // epilogue: C/D layout col=lane&15, row=(lane>>4)*4+j  (verified)
    const int ccol = wc * 32 + (lane & 15);
    float bv[2];
    #pragma unroll
    for (int nt = 0; nt < 2; nt++) bv[nt] = bias[n0 + ccol + nt * 16];

    if (MODE == 0) {
        #pragma unroll
        for (int mt = 0; mt < 4; mt++) {
            #pragma unroll
            for (int j = 0; j < 4; j++) {
                int row = m0 + wr * 64 + mt * 16 + (lane >> 4) * 4 + j;
                #pragma unroll
                for (int nt = 0; nt < 2; nt++) {
                    float v = gelu_f(acc[mt][nt][j] + bv[nt]);
                    Cdst[(size_t)row * NTOT + n0 + ccol + nt * 16] = f2bf(v);
                }
            }
        }
    } else {
        #pragma unroll
        for (int mt = 0; mt < 4; mt++) {
            #pragma unroll
            for (int j = 0; j < 4; j++) {
                int grow = rbase + wr * 64 + mt * 16 + (lane >> 4) * 4 + j;
                #pragma unroll
                for (int nt = 0; nt < 2; nt++) {
                    float v = acc[mt][nt][j] + bv[nt];
                    Cdst[(size_t)grow * NTOT + n0 + ccol + nt * 16] = f2bf(v);
                }
            }
        }
    }
}

// ---------------- combine: out[token] = g1*y[r1] + g2*y[r2] ----------------
__global__ void k_combine(const ushort* __restrict__ y,
                          const int* __restrict__ r1, const int* __restrict__ r2,
                          const float* __restrict__ g1, const float* __restrict__ g2,
                          float* __restrict__ out) {
    int t = blockIdx.x;
    int d = threadIdx.x;          // 192 threads, 4 floats each
    int a = r1[t], b = r2[t];
    float wa = g1[t], wb = g2[t];
    size_t opos;
    if (t < NDET) { int bb = t >> 10, s = t & 1023; opos = ((size_t)bb * 1280 + s) * 768; }
    else { int tt = t - NDET; int bb = tt >> 8, s = tt & 255; opos = ((size_t)bb * 1280 + 1024 + s) * 768; }
    int di = d * 4;
    float4 o = make_float4(0.f, 0.f, 0.f, 0.f);
    if (a >= 0) {
        uint2 v = *(const uint2*)(y + (size_t)a * 768 + di);
        o.x += wa * bf2f(v.x & 0xffffu); o.y += wa * bf2f(v.x >> 16);
        o.z += wa * bf2f(v.y & 0xffffu); o.w += wa * bf2f(v.y >> 16);
    }
    if (b >= 0) {
        uint2 v = *(const uint2*)(y + (size_t)b * 768 + di);
        o.x += wb * bf2f(v.x & 0xffffu); o.y += wb * bf2f(v.x >> 16);
        o.z += wb * bf2f(v.y & 0xffffu); o.w += wb * bf2f(v.y >> 16);
    }
    *(float4*)(out + opos + di) = o;
}

extern "C" void kernel_launch(void* const* d_in, const int* in_sizes, int n_in,
                              void* d_out, int out_size, void* d_ws, size_t ws_size,
                              hipStream_t stream) {
    const float* xd  = (const float*)d_in[0];
    const float* xc  = (const float*)d_in[1];
    const float* wrd = (const float*)d_in[2];
    const float* wrc = (const float*)d_in[3];
    const float* w1  = (const float*)d_in[4];
    const float* b1  = (const float*)d_in[5];
    const float* w2  = (const float*)d_in[6];
    const float* b2  = (const float*)d_in[7];
    float* out = (float*)d_out;

    size_t off = 0;
    char* base = (char*)d_ws;
    auto alloc = [&](size_t bytes) -> char* {
        char* r = base + off;
        off += (bytes + 255) & ~(size_t)255;
        return r;
    };
    ushort* xbf = (ushort*)alloc((size_t)NTOK * DMODEL * 2);
    ushort* w1t = (ushort*)alloc((size_t)NE * MLPDIM * DMODEL * 2);
    ushort* w2t = (ushort*)alloc((size_t)NE * DMODEL * MLPDIM * 2);
    ushort* y   = (ushort*)alloc((size_t)TOT_ROWS * DMODEL * 2);
    int*   slot_map = (int*)alloc((size_t)TOT_ROWS * 4);
    int*   e1 = (int*)alloc((size_t)NTOK * 4);
    int*   e2 = (int*)alloc((size_t)NTOK * 4);
    float* g1 = (float*)alloc((size_t)NTOK * 4);
    float* g2 = (float*)alloc((size_t)NTOK * 4);
    int*   r1 = (int*)alloc((size_t)NTOK * 4);
    int*   r2 = (int*)alloc((size_t)NTOK * 4);

    // pick the largest expert-chunk whose h buffer fits the workspace
    const size_t h_per_e = (size_t)ROWS_PER_E * MLPDIM * 2;   // 31.5 MB
    int chunkE = 0;
    for (int c = NE; c >= 2; c >>= 1)
        if (off + c * h_per_e <= ws_size) { chunkE = c; break; }
    if (!chunkE) return;
    ushort* h = (ushort*)alloc((size_t)chunkE * h_per_e);

    hipMemsetAsync(slot_map, 0xFF, (size_t)TOT_ROWS * 4, stream);   // -1 = empty

    k_router<<<NTOK / 4, 256, 0, stream>>>(xd, xc, wrd, wrc, xbf, e1, e2, g1, g2);
    k_transpose_bf<<<dim3(MLPDIM / 32, DMODEL / 32, NE), dim3(8, 32), 0, stream>>>(w1, w1t, DMODEL, MLPDIM);
    k_transpose_bf<<<dim3(DMODEL / 32, MLPDIM / 32, NE), dim3(8, 32), 0, stream>>>(w2, w2t, MLPDIM, DMODEL);
    k_scan<<<24, 64, 0, stream>>>(e1, e2, slot_map, r1, r2);

    for (int e0 = 0; e0 < NE; e0 += chunkE) {
        int nmb = chunkE * (ROWS_PER_E / 128);               // m-blocks in chunk
        k_gemm<DMODEL, MLPDIM, 0><<<nmb * (MLPDIM / 128), 512, 0, stream>>>(
            xbf, slot_map, w1t, b1, h, e0);
        k_gemm<MLPDIM, DMODEL, 1><<<nmb * (DMODEL / 128), 512, 0, stream>>>(
            h, slot_map, w2t, b2, y, e0);
    }

    k_combine<<<NTOK, 192, 0, stream>>>(y, r1, r2, g1, g2, out);
}